// Round 4
// baseline (851.839 us; speedup 1.0000x reference)
//
#include <hip/hip_runtime.h>
#include <stdint.h>

#define CA 64     // in channels
#define CB 128    // out channels
#define KOFF 27   // 3^3 offsets
#define BN_EPS 1e-4f

typedef short bf16x8 __attribute__((ext_vector_type(8)));
typedef float f32x4 __attribute__((ext_vector_type(4)));
typedef unsigned int u32x4 __attribute__((ext_vector_type(4)));
typedef unsigned short u16x4 __attribute__((ext_vector_type(4)));

__device__ __forceinline__ unsigned short f2bf(float f) {
  union { float f; uint32_t u; } c; c.f = f;
  uint32_t u = c.u;
  return (unsigned short)((u + 0x7FFFu + ((u >> 16) & 1u)) >> 16);  // RNE
}

// ---- mask dtype detection: if int32 layout, bytes at i%4!=0 are all zero ----
__global__ void detect_mask_k(const unsigned char* __restrict__ m, int* flag) {
  unsigned v = 0;
  for (int i = threadIdx.x; i < 4096; i += 256)
    if (i & 3) v |= m[i];
  if (v) atomicOr(flag, 1);   // 1 => byte/bool layout, 0 => int32 layout
}

__global__ void pack_mask_k(const void* __restrict__ mp, const int* __restrict__ flag,
                            uint32_t* __restrict__ bits, int n) {
  int i = blockIdx.x * blockDim.x + threadIdx.x;
  if (i >= n) return;
  uint32_t b = 0;
  if (*flag) {
    const unsigned char* m = (const unsigned char*)mp + (size_t)i * KOFF;
    for (int k = 0; k < KOFF; k++) b |= (m[k] ? 1u : 0u) << k;
  } else {
    const int* m = (const int*)mp + (size_t)i * KOFF;
    for (int k = 0; k < KOFF; k++) b |= (m[k] ? 1u : 0u) << k;
  }
  bits[i] = b;
}

// ---- all weight transposes + bf16 convert in one launch ----
// wt[k][co][ci] = bf16(w[k][ci][co])
__global__ void transpose_all_k(const float* __restrict__ W1, const float* __restrict__ W2,
                                const float* __restrict__ Wnin,
                                unsigned short* __restrict__ w1t, unsigned short* __restrict__ w2t,
                                unsigned short* __restrict__ wnt) {
  const int t1 = KOFF * CA * CB, t2 = KOFF * CB * CB, t3 = CA * CB;
  int idx = blockIdx.x * blockDim.x + threadIdx.x;
  if (idx < t1) {
    int ci = idx % CA; int r = idx / CA; int co = r % CB; int k = r / CB;
    w1t[idx] = f2bf(W1[((size_t)k * CA + ci) * CB + co]);
  } else if (idx < t1 + t2) {
    int j = idx - t1;
    int ci = j % CB; int r = j / CB; int co = r % CB; int k = r / CB;
    w2t[j] = f2bf(W2[((size_t)k * CB + ci) * CB + co]);
  } else if (idx < t1 + t2 + t3) {
    int j = idx - t1 - t2;
    int ci = j % CA; int co = j / CA;
    wnt[j] = f2bf(Wnin[(size_t)ci * CB + co]);
  }
}

// ---- per-channel sum & sumsq (training-mode BN stats) ----
template<int C>
__global__ void col_stats_k(const float* __restrict__ x, int n, float* __restrict__ sums) {
  __shared__ float ssum[C], ssq[C];
  int t = threadIdx.x;
  for (int i = t; i < C; i += 256) { ssum[i] = 0.f; ssq[i] = 0.f; }
  __syncthreads();
  const int c = t % C;
  const int rpb = 256 / C;
  float s = 0.f, q = 0.f;
  for (int r = blockIdx.x * rpb + t / C; r < n; r += gridDim.x * rpb) {
    float v = x[(size_t)r * C + c];
    s += v; q += v * v;
  }
  atomicAdd(&ssum[c], s);
  atomicAdd(&ssq[c], q);
  __syncthreads();
  for (int i = t; i < C; i += 256) {
    atomicAdd(&sums[i], ssum[i]);
    atomicAdd(&sums[C + i], ssq[i]);
  }
}

template<int C>
__global__ void bn_finalize_k(const float* __restrict__ sums, const float* __restrict__ gamma,
                              const float* __restrict__ beta, float* __restrict__ sc, int n) {
  int c = threadIdx.x;
  if (c >= C) return;
  float inv_n = 1.f / (float)n;
  float mean = sums[c] * inv_n;
  float var = sums[C + c] * inv_n - mean * mean;
  float rstd = rsqrtf(var + BN_EPS);
  float scale = gamma[c] * rstd;
  sc[c] = scale;
  sc[C + c] = beta[c] - mean * scale;
}

template<int C, bool RAW>
__global__ void bn_apply_k(const float* __restrict__ x, const float* __restrict__ sc,
                           unsigned short* __restrict__ h, unsigned short* __restrict__ raw,
                           int total) {
  int idx = (blockIdx.x * blockDim.x + threadIdx.x) * 4;
  if (idx >= total) return;
  f32x4 v = *(const f32x4*)&x[idx];
  int c0 = idx % C;
  u16x4 ho, ro;
#pragma unroll
  for (int j = 0; j < 4; j++) {
    float s = sc[c0 + j], b = sc[C + c0 + j];
    float hv = fmaxf(v[j] * s + b, 0.f);
    ho[j] = f2bf(hv);
    if (RAW) ro[j] = f2bf(v[j]);
  }
  *(u16x4*)&h[idx] = ho;
  if (RAW) *(u16x4*)&raw[idx] = ro;
}

// ---- barrier-free register-gather GEMM subconv ----
// out[n,:] = sum_k mask[n,k] * hin[nbr[n,k],:] @ W[k]   (+ FUSE: fbraw @ wnt)
// Block: 64 rows x 128 cols, 256 threads; wave w owns cols [w*32, w*32+32).
// NO LDS, NO barriers: the MFMA A-fragment for row r is a contiguous 16B chunk
// of hin[nbr[r,k]], so each lane gathers its fragment straight from global into
// the MFMA operand register (lane layout: row=l&15, k-cols quad*8, per 32-chunk).
// Each wave re-gathers all 64 rows (4x L2-side traffic; block's waves read the
// same 16KB/iter nearly simultaneously -> L1 dedupes). nbr indices read direct
// from global too (block-local 6.9KB, L1-hot) -- no staging prologue.
// R0-R3 showed the cooperative-LDS-tile + per-iteration-barrier structure is
// phase-serialized (all pipes <31% busy, dur invariant ~220us across tuning);
// this removes the coupling: independent in-order waves, 2-group register
// pipeline, vmcnt-counted waits only, fully unrolled (KOFF*NKS groups).
template<int CIN, bool FUSE, bool STATS>
__launch_bounds__(256)
__global__ void conv_k(const unsigned short* __restrict__ hin,
                       const unsigned short* __restrict__ wt,
                       const int* __restrict__ nbr,
                       const uint32_t* __restrict__ mbits,
                       const unsigned short* __restrict__ fbraw,
                       const unsigned short* __restrict__ wnt,
                       float* __restrict__ out, float* __restrict__ sums, int n) {
  constexpr int TR = 64;
  constexpr int NKS = CIN / 32;     // 32-wide K chunks per offset (2 or 4)
  constexpr int NG = KOFF * NKS;    // total pipeline groups

  const int t = threadIdx.x;
  const int lane = t & 63;
  const int wave = t >> 6;
  const int l16 = lane & 15;
  const int quad = lane >> 4;
  const int colbase = wave * 32;
  const int rowbase = blockIdx.x * TR;
  const int nrows = min(TR, n - rowbase);

  // per-lane fixed rows: row(rt) = rt*16 + l16
  uint32_t pm[4];   // mask bits per owned row
  int nbo[4];       // element offset of that row's nbr[] slice
#pragma unroll
  for (int rt = 0; rt < 4; rt++) {
    int r = rt * 16 + l16;
    bool ok = r < nrows;
    pm[rt] = ok ? mbits[rowbase + r] : 0u;
    nbo[rt] = (ok ? (rowbase + r) : rowbase) * KOFF;  // clamped: loads predicated off anyway
  }

  const char* hq  = (const char*)hin + quad * 16;                      // + row*CIN*2 + ks*64
  const char* wq0 = (const char*)wt + ((colbase + l16) * CIN + quad * 8) * 2;
  const char* wq1 = wq0 + 16 * CIN * 2;

  f32x4 acc[4][2];
#pragma unroll
  for (int i = 0; i < 4; i++) { acc[i][0] = f32x4{0,0,0,0}; acc[i][1] = f32x4{0,0,0,0}; }

  // nbr index pipeline, 3 k-slots (k mod 3); A/B fragment sets by group parity
  int nb0[4], nb1[4], nb2[4];
  bf16x8 aA[4], aB[4];
  bf16x8 bA0, bA1, bB0, bB1;

#define LDNB_BODY(kk, nb)                                                      \
    { _Pragma("unroll")                                                        \
      for (int rt = 0; rt < 4; rt++) nb[rt] = nbr[nbo[rt] + (kk)]; }
#define LDNB(kk) do {                                                          \
    if (((kk) % 3) == 0)      LDNB_BODY(kk, nb0)                               \
    else if (((kk) % 3) == 1) LDNB_BODY(kk, nb1)                               \
    else                      LDNB_BODY(kk, nb2)                               \
  } while (0)

#define LOADA_BODY(kk, ks, nb, a)                                              \
    { _Pragma("unroll")                                                        \
      for (int rt = 0; rt < 4; rt++) {                                         \
        bf16x8 v = bf16x8{0, 0, 0, 0, 0, 0, 0, 0};                             \
        if ((pm[rt] >> (kk)) & 1u)                                             \
          v = *(const bf16x8*)(hq +                                            \
                (size_t)((unsigned)nb[rt] * (unsigned)(CIN * 2)) + (ks) * 64); \
        a[rt] = v; } }
#define LOADA(kk, ks, a) do {                                                  \
    if (((kk) % 3) == 0)      LOADA_BODY(kk, ks, nb0, a)                       \
    else if (((kk) % 3) == 1) LOADA_BODY(kk, ks, nb1, a)                       \
    else                      LOADA_BODY(kk, ks, nb2, a)                       \
  } while (0)

#define LOADW(kk, ks, b0, b1) do {                                             \
    int woff = (kk) * (CB * CIN * 2) + (ks) * 64;                              \
    b0 = *(const bf16x8*)(wq0 + woff);                                         \
    b1 = *(const bf16x8*)(wq1 + woff);                                         \
  } while (0)

#define MMA8(a, b0, b1) do {                                                   \
    _Pragma("unroll")                                                          \
    for (int rt = 0; rt < 4; rt++) {                                           \
      acc[rt][0] = __builtin_amdgcn_mfma_f32_16x16x32_bf16(a[rt], b0, acc[rt][0], 0, 0, 0); \
      acc[rt][1] = __builtin_amdgcn_mfma_f32_16x16x32_bf16(a[rt], b1, acc[rt][1], 0, 0, 0); \
    } } while (0)

  // ---- prologue: nbr for k=0,1; fragment groups (0,0)->A, (0,1)->B ----
  LDNB(0);
  LDNB(1);
  LOADA(0, 0, aA); LOADW(0, 0, bA0, bA1);
  LOADA(0, 1, aB); LOADW(0, 1, bB0, bB1);

  if constexpr (FUSE) {
    // NiN shortcut: acc += fbraw @ wnt, straight from global; covers the
    // prologue gathers' latency.
#pragma unroll
    for (int ks = 0; ks < CA / 32; ks++) {
      bf16x8 b0 = *(const bf16x8*)&wnt[(colbase + l16) * CA + ks * 32 + quad * 8];
      bf16x8 b1 = *(const bf16x8*)&wnt[(colbase + 16 + l16) * CA + ks * 32 + quad * 8];
#pragma unroll
      for (int rt = 0; rt < 4; rt++) {
        int r = rt * 16 + l16;
        bf16x8 a = bf16x8{0, 0, 0, 0, 0, 0, 0, 0};
        if (r < nrows)
          a = *(const bf16x8*)&fbraw[(size_t)(rowbase + r) * CA + ks * 32 + quad * 8];
        acc[rt][0] = __builtin_amdgcn_mfma_f32_16x16x32_bf16(a, b0, acc[rt][0], 0, 0, 0);
        acc[rt][1] = __builtin_amdgcn_mfma_f32_16x16x32_bf16(a, b1, acc[rt][1], 0, 0, 0);
      }
    }
  }

  // ---- main: fully unrolled group pipeline (compute g, load g+2) ----
#pragma unroll
  for (int g = 0; g < NG; g++) {
    const int k = g / NKS, ks = g % NKS;
    (void)ks;
    if ((g & 1) == 0) MMA8(aA, bA0, bA1); else MMA8(aB, bB0, bB1);
    if ((g % NKS) == 0 && k + 2 < KOFF) LDNB(k + 2);   // nbr two k's ahead
    const int g2 = g + 2;
    if (g2 < NG) {
      const int k2 = g2 / NKS, ks2 = g2 % NKS;
      if ((g & 1) == 0) { LOADA(k2, ks2, aA); LOADW(k2, ks2, bA0, bA1); }
      else              { LOADA(k2, ks2, aB); LOADW(k2, ks2, bB0, bB1); }
    }
  }
#undef LDNB_BODY
#undef LDNB
#undef LOADA_BODY
#undef LOADA
#undef LOADW
#undef MMA8

  // epilogue: C/D layout col=lane&15, row=(lane>>4)*4+reg
#pragma unroll
  for (int rt = 0; rt < 4; rt++) {
#pragma unroll
    for (int ct = 0; ct < 2; ct++) {
#pragma unroll
      for (int i = 0; i < 4; i++) {
        int r = rt * 16 + quad * 4 + i;
        if (r < nrows) {
          int c = colbase + ct * 16 + l16;
          out[(size_t)(rowbase + r) * CB + c] = acc[rt][ct][i];
        }
      }
    }
  }

  if constexpr (STATS) {
    // fused next-BN stats: tail rows contribute exact zeros (masked gathers)
#pragma unroll
    for (int ct = 0; ct < 2; ct++) {
      float s = 0.f, q = 0.f;
#pragma unroll
      for (int rt = 0; rt < 4; rt++)
#pragma unroll
        for (int i = 0; i < 4; i++) { float v = acc[rt][ct][i]; s += v; q += v * v; }
      s += __shfl_xor(s, 16); s += __shfl_xor(s, 32);   // reduce over quad lanes
      q += __shfl_xor(q, 16); q += __shfl_xor(q, 32);
      if (quad == 0) {
        int cch = colbase + ct * 16 + l16;
        atomicAdd(&sums[cch], s);
        atomicAdd(&sums[CB + cch], q);
      }
    }
  }
}

extern "C" void kernel_launch(void* const* d_in, const int* in_sizes, int n_in,
                              void* d_out, int out_size, void* d_ws, size_t ws_size,
                              hipStream_t stream) {
  const float* feat   = (const float*)d_in[0];
  const float* gamma1 = (const float*)d_in[1];
  const float* beta1  = (const float*)d_in[2];
  const float* W1     = (const float*)d_in[3];
  const float* gamma2 = (const float*)d_in[4];
  const float* beta2  = (const float*)d_in[5];
  const float* W2     = (const float*)d_in[6];
  const float* Wnin   = (const float*)d_in[7];
  const int*   nbr    = (const int*)d_in[8];
  const void*  mask   = d_in[9];
  float* out = (float*)d_out;

  const int n = in_sizes[0] / CA;  // 100000

  char* ws = (char*)d_ws;
  size_t off = 0;
  auto alloc = [&](size_t bytes) { size_t p = off; off += (bytes + 255) & ~(size_t)255; return p; };
  int*            flag  = (int*)           (ws + alloc(256));
  float*          sums1 = (float*)         (ws + alloc(2 * CA * 4));
  float*          sums2 = (float*)         (ws + alloc(2 * CB * 4));
  float*          sc1   = (float*)         (ws + alloc(2 * CA * 4));
  float*          sc2   = (float*)         (ws + alloc(2 * CB * 4));
  uint32_t*       mbits = (uint32_t*)      (ws + alloc((size_t)n * 4));
  unsigned short* fb    = (unsigned short*)(ws + alloc((size_t)n * CA * 2));
  unsigned short* hb1   = (unsigned short*)(ws + alloc((size_t)n * CA * 2));
  float*          out1  = (float*)         (ws + alloc((size_t)n * CB * 4));
  unsigned short* hb2   = (unsigned short*)(ws + alloc((size_t)n * CB * 2));
  unsigned short* w1t   = (unsigned short*)(ws + alloc((size_t)KOFF * CB * CA * 2));
  unsigned short* w2t   = (unsigned short*)(ws + alloc((size_t)KOFF * CB * CB * 2));
  unsigned short* wnt   = (unsigned short*)(ws + alloc((size_t)CB * CA * 2));

  // zero flag + stats accumulators (ws is poisoned 0xAA before every launch)
  hipMemsetAsync(d_ws, 0, 1792, stream);

  detect_mask_k<<<1, 256, 0, stream>>>((const unsigned char*)mask, flag);
  pack_mask_k<<<(n + 255) / 256, 256, 0, stream>>>(mask, flag, mbits, n);

  {
    int tot = KOFF * CA * CB + KOFF * CB * CB + CA * CB;
    transpose_all_k<<<(tot + 255) / 256, 256, 0, stream>>>(W1, W2, Wnin, w1t, w2t, wnt);
  }

  // stage 1: BN stats -> scale/shift -> h1 (bn+relu bf16) + raw feat bf16
  col_stats_k<CA><<<256, 256, 0, stream>>>(feat, n, sums1);
  bn_finalize_k<CA><<<1, CA, 0, stream>>>(sums1, gamma1, beta1, sc1, n);
  bn_apply_k<CA, true><<<(n * CA / 4 + 255) / 256, 256, 0, stream>>>(feat, sc1, hb1, fb, n * CA);

  // conv1: out1 = subconv(h1, W1)  [N,128] fp32, BN2 stats fused in epilogue
  conv_k<CA, false, true><<<(n + 63) / 64, 256, 0, stream>>>(hb1, w1t, nbr, mbits, nullptr, nullptr, out1, sums2, n);

  // stage 2 (col_stats pass eliminated -- stats came from conv1)
  bn_finalize_k<CB><<<1, CB, 0, stream>>>(sums2, gamma2, beta2, sc2, n);
  bn_apply_k<CB, false><<<(n * CB / 4 + 255) / 256, 256, 0, stream>>>(out1, sc2, hb2, nullptr, n * CB);

  // conv2 + fused NiN shortcut
  conv_k<CB, true, false><<<(n + 63) / 64, 256, 0, stream>>>(hb2, w2t, nbr, mbits, fb, wnt, out, nullptr, n);
}

// Round 5
// 513.660 us; speedup vs baseline: 1.6584x; 1.6584x over previous
//
#include <hip/hip_runtime.h>
#include <stdint.h>

#define CA 64     // in channels
#define CB 128    // out channels
#define KOFF 27   // 3^3 offsets
#define BN_EPS 1e-4f

typedef short bf16x8 __attribute__((ext_vector_type(8)));
typedef float f32x4 __attribute__((ext_vector_type(4)));
typedef unsigned int u32x4 __attribute__((ext_vector_type(4)));
typedef unsigned short u16x4 __attribute__((ext_vector_type(4)));

__device__ __forceinline__ unsigned short f2bf(float f) {
  union { float f; uint32_t u; } c; c.f = f;
  uint32_t u = c.u;
  return (unsigned short)((u + 0x7FFFu + ((u >> 16) & 1u)) >> 16);  // RNE
}

// ---- mask dtype detection: if int32 layout, bytes at i%4!=0 are all zero ----
__global__ void detect_mask_k(const unsigned char* __restrict__ m, int* flag) {
  unsigned v = 0;
  for (int i = threadIdx.x; i < 4096; i += 256)
    if (i & 3) v |= m[i];
  if (v) atomicOr(flag, 1);   // 1 => byte/bool layout, 0 => int32 layout
}

__global__ void pack_mask_k(const void* __restrict__ mp, const int* __restrict__ flag,
                            uint32_t* __restrict__ bits, int n) {
  int i = blockIdx.x * blockDim.x + threadIdx.x;
  if (i >= n) return;
  uint32_t b = 0;
  if (*flag) {
    const unsigned char* m = (const unsigned char*)mp + (size_t)i * KOFF;
    for (int k = 0; k < KOFF; k++) b |= (m[k] ? 1u : 0u) << k;
  } else {
    const int* m = (const int*)mp + (size_t)i * KOFF;
    for (int k = 0; k < KOFF; k++) b |= (m[k] ? 1u : 0u) << k;
  }
  bits[i] = b;
}

// ---- all weight transposes + bf16 convert in one launch ----
// wt[k][co][ci] = bf16(w[k][ci][co])
__global__ void transpose_all_k(const float* __restrict__ W1, const float* __restrict__ W2,
                                const float* __restrict__ Wnin,
                                unsigned short* __restrict__ w1t, unsigned short* __restrict__ w2t,
                                unsigned short* __restrict__ wnt) {
  const int t1 = KOFF * CA * CB, t2 = KOFF * CB * CB, t3 = CA * CB;
  int idx = blockIdx.x * blockDim.x + threadIdx.x;
  if (idx < t1) {
    int ci = idx % CA; int r = idx / CA; int co = r % CB; int k = r / CB;
    w1t[idx] = f2bf(W1[((size_t)k * CA + ci) * CB + co]);
  } else if (idx < t1 + t2) {
    int j = idx - t1;
    int ci = j % CB; int r = j / CB; int co = r % CB; int k = r / CB;
    w2t[j] = f2bf(W2[((size_t)k * CB + ci) * CB + co]);
  } else if (idx < t1 + t2 + t3) {
    int j = idx - t1 - t2;
    int ci = j % CA; int co = j / CA;
    wnt[j] = f2bf(Wnin[(size_t)ci * CB + co]);
  }
}

// ---- per-channel sum & sumsq (training-mode BN stats) ----
template<int C>
__global__ void col_stats_k(const float* __restrict__ x, int n, float* __restrict__ sums) {
  __shared__ float ssum[C], ssq[C];
  int t = threadIdx.x;
  for (int i = t; i < C; i += 256) { ssum[i] = 0.f; ssq[i] = 0.f; }
  __syncthreads();
  const int c = t % C;
  const int rpb = 256 / C;
  float s = 0.f, q = 0.f;
  for (int r = blockIdx.x * rpb + t / C; r < n; r += gridDim.x * rpb) {
    float v = x[(size_t)r * C + c];
    s += v; q += v * v;
  }
  atomicAdd(&ssum[c], s);
  atomicAdd(&ssq[c], q);
  __syncthreads();
  for (int i = t; i < C; i += 256) {
    atomicAdd(&sums[i], ssum[i]);
    atomicAdd(&sums[C + i], ssq[i]);
  }
}

template<int C>
__global__ void bn_finalize_k(const float* __restrict__ sums, const float* __restrict__ gamma,
                              const float* __restrict__ beta, float* __restrict__ sc, int n) {
  int c = threadIdx.x;
  if (c >= C) return;
  float inv_n = 1.f / (float)n;
  float mean = sums[c] * inv_n;
  float var = sums[C + c] * inv_n - mean * mean;
  float rstd = rsqrtf(var + BN_EPS);
  float scale = gamma[c] * rstd;
  sc[c] = scale;
  sc[C + c] = beta[c] - mean * scale;
}

template<int C, bool RAW>
__global__ void bn_apply_k(const float* __restrict__ x, const float* __restrict__ sc,
                           unsigned short* __restrict__ h, unsigned short* __restrict__ raw,
                           int total) {
  int idx = (blockIdx.x * blockDim.x + threadIdx.x) * 4;
  if (idx >= total) return;
  f32x4 v = *(const f32x4*)&x[idx];
  int c0 = idx % C;
  u16x4 ho, ro;
#pragma unroll
  for (int j = 0; j < 4; j++) {
    float s = sc[c0 + j], b = sc[C + c0 + j];
    float hv = fmaxf(v[j] * s + b, 0.f);
    ho[j] = f2bf(hv);
    if (RAW) ro[j] = f2bf(v[j]);
  }
  *(u16x4*)&h[idx] = ho;
  if (RAW) *(u16x4*)&raw[idx] = ro;
}

// ---- DMA-staged gather-GEMM subconv ----
// out[n,:] = sum_k mask[n,k] * hin[nbr[n,k],:] @ W[k]   (+ FUSE: fbraw @ wnt)
// Block: 64 rows x 128 cols, 256 threads (4 waves of 64x32).
// Staging uses global_load_lds DMA: per-lane GLOBAL gather address (allowed),
// wave-linear LDS dest. The XOR bank swizzle is applied on the SOURCE side
// (thread fetches logical chunk c16^(grow&(CH-1)), writes linearly) so the
// stored layout matches R3's verified conflict-free layout; read side is
// unchanged. Masked rows fetch from a 16B zero page. This removes per iter:
// 4 ds_writes, 4 lnbr ds_reads, the 16-dword VGPR staging round-trip, and the
// store-side lgkm chain (R0-R3 critical path). DMA for k+1 issues at the TOP
// of iter k (full-iteration latency cover) and drains with a COUNTED
// s_waitcnt vmcnt(2*NKS) fused with s_barrier (leaves only next B-loads in
// flight). sched_barrier(0) after the DMA+nbr cluster pins issue order so the
// count is exact. LDS = 2*TR*CIN*2 only: 32KB (conv2, 5 blk/CU), 16KB (conv1).
// R4 lesson: gathers MUST issue exactly once per block (per-wave re-gather
// quadrupled TA cacheline traffic, 396us). No min-occupancy bound (R1 spill).
template<int CIN, bool FUSE, bool STATS>
__launch_bounds__(256)
__global__ void conv_k(const unsigned short* __restrict__ hin,
                       const unsigned short* __restrict__ wt,
                       const int* __restrict__ nbr,
                       const uint32_t* __restrict__ mbits,
                       const unsigned short* __restrict__ fbraw,
                       const unsigned short* __restrict__ wnt,
                       const char* __restrict__ zpage,
                       float* __restrict__ out, float* __restrict__ sums, int n) {
  constexpr int TR = 64;
  constexpr int NKS = CIN / 32;     // MFMA K-steps per offset (2 or 4)
  constexpr int CH = CIN / 8;       // 16B chunks per row (8 or 16)
  constexpr int RPP = 256 / CH;     // rows per staging pass (block-wide)
  constexpr int RPW = 64 / CH;      // rows per wave per pass
  constexpr int NP = TR / RPP;      // staging passes (2 or 4)

  __shared__ alignas(16) unsigned short tile[2][TR * CIN];

  const int t = threadIdx.x;
  const int lane = t & 63;
  const int wave = t >> 6;
  const int l16 = lane & 15;
  const int quad = lane >> 4;
  const int colbase = wave * 32;
  const int rowbase = blockIdx.x * TR;
  const int nrows = min(TR, n - rowbase);

  const int c16 = t % CH;           // phys 16B chunk this lane's DMA writes
  const int grow = t / CH;          // row-within-pass (== wave*RPW + l/CH)
  // source-side swizzle: fetch logical chunk c16^(grow&(CH-1)) -> stored
  // layout identical to R3's verified conflict-free layout.
  const char* hsrc = (const char*)hin + (c16 ^ (grow & (CH - 1))) * 16;
  const int wvrow = wave * RPW;     // wave-uniform base row within a pass

  uint32_t pm[NP]; int nbro[NP];
#pragma unroll
  for (int p = 0; p < NP; p++) {
    int rg = rowbase + p * RPP + grow;
    pm[p] = (rg < n) ? mbits[rg] : 0u;
    nbro[p] = min(rg, n - 1) * KOFF;  // clamped: masked lanes use zpage anyway
  }

  const int boff0 = (colbase + l16) * CIN + quad * 8;
  const int boff1 = boff0 + 16 * CIN;

  f32x4 acc[4][2];
#pragma unroll
  for (int i = 0; i < 4; i++) { acc[i][0] = f32x4{0,0,0,0}; acc[i][1] = f32x4{0,0,0,0}; }

  bf16x8 bfr[2 * NKS];          // single-deep B fragments
  int nbE[NP], nbO[NP];         // nbr regs, parity by k (static indexing)

#define NBLOAD(kk, nb)                                                         \
  { _Pragma("unroll")                                                          \
    for (int p = 0; p < NP; p++) nb[p] = nbr[nbro[p] + (kk)]; }

#define DMASTAGE(kk, buf, nb)                                                  \
  { _Pragma("unroll")                                                          \
    for (int p = 0; p < NP; p++) {                                             \
      const char* g = ((pm[p] >> (kk)) & 1u)                                   \
          ? hsrc + (size_t)((unsigned)nb[p] * (unsigned)(CIN * 2))             \
          : zpage;                                                             \
      __builtin_amdgcn_global_load_lds(                                        \
          (const __attribute__((address_space(1))) void*)g,                    \
          (__attribute__((address_space(3))) void*)                            \
              &tile[buf][(p * RPP + wvrow) * CIN],                             \
          16, 0, 0);                                                           \
    } }

#define LOADB(kk, dst)                                                         \
  {                                                                            \
    const unsigned short* wk = wt + (size_t)(kk) * (CB * CIN);                 \
    _Pragma("unroll")                                                          \
    for (int ks = 0; ks < NKS; ks++) {                                         \
      dst[2 * ks]     = *(const bf16x8*)&wk[boff0 + ks * 32];                  \
      dst[2 * ks + 1] = *(const bf16x8*)&wk[boff1 + ks * 32];                  \
    }                                                                          \
  }

#define MMA(buf)                                                               \
  {                                                                            \
    _Pragma("unroll")                                                          \
    for (int ks = 0; ks < NKS; ks++) {                                         \
      _Pragma("unroll")                                                        \
      for (int rt = 0; rt < 4; rt++) {                                         \
        int row = rt * 16 + l16;                                               \
        bf16x8 a = *(const bf16x8*)&tile[buf][row * CIN +                      \
                      (((ks * 4 + quad) ^ (row & (CH - 1))) * 8)];             \
        acc[rt][0] = __builtin_amdgcn_mfma_f32_16x16x32_bf16(a, bfr[2 * ks],     acc[rt][0], 0, 0, 0); \
        acc[rt][1] = __builtin_amdgcn_mfma_f32_16x16x32_bf16(a, bfr[2 * ks + 1], acc[rt][1], 0, 0, 0); \
      }                                                                        \
    }                                                                          \
  }

// counted drain: leaves exactly the 2*NKS B-loads in flight, drains DMA+nbr.
#define WAITBAR()                                                              \
  asm volatile("s_waitcnt vmcnt(%0) lgkmcnt(0)\n\ts_barrier"                   \
               :: "i"(2 * NKS) : "memory")

  // ---- prologue ----
  NBLOAD(0, nbE);               // addr dependency forces its own wait
  DMASTAGE(0, 0, nbE);
  NBLOAD(1, nbO);
  __builtin_amdgcn_sched_barrier(0);   // nothing hoists above the DMA

  if constexpr (FUSE) {
    // NiN shortcut: acc += fbraw @ wnt, straight from global (the 16B A-frag
    // IS a contiguous row chunk); its MFMAs cover the prologue DMA latency.
#pragma unroll
    for (int ks = 0; ks < CA / 32; ks++) {
      bf16x8 b0 = *(const bf16x8*)&wnt[(colbase + l16) * CA + ks * 32 + quad * 8];
      bf16x8 b1 = *(const bf16x8*)&wnt[(colbase + 16 + l16) * CA + ks * 32 + quad * 8];
#pragma unroll
      for (int rt = 0; rt < 4; rt++) {
        int r = rt * 16 + l16;
        bf16x8 a = bf16x8{0, 0, 0, 0, 0, 0, 0, 0};
        if (r < nrows)
          a = *(const bf16x8*)&fbraw[(size_t)(rowbase + r) * CA + ks * 32 + quad * 8];
        acc[rt][0] = __builtin_amdgcn_mfma_f32_16x16x32_bf16(a, b0, acc[rt][0], 0, 0, 0);
        acc[rt][1] = __builtin_amdgcn_mfma_f32_16x16x32_bf16(a, b1, acc[rt][1], 0, 0, 0);
      }
    }
  }

  LOADB(0, bfr);
  WAITBAR();                    // tile[0] resident; B(0) stays in flight

  // ---- main loop: FULL unroll, parity-static nb buffers ----
#pragma unroll
  for (int k = 0; k < KOFF; k++) {
    const int cur = k & 1, nxt = cur ^ 1;
    if (k + 1 < KOFF) {
      if (((k + 1) & 1) == 0) DMASTAGE(k + 1, nxt, nbE) else DMASTAGE(k + 1, nxt, nbO);
      if (k + 2 < KOFF) {
        if (((k + 2) & 1) == 0) NBLOAD(k + 2, nbE) else NBLOAD(k + 2, nbO);
      }
      __builtin_amdgcn_sched_barrier(0);  // keep B-loads below the DMA
    }
    MMA(cur);
    if (k + 1 < KOFF) {
      LOADB(k + 1, bfr);
      WAITBAR();
    }
  }
#undef NBLOAD
#undef DMASTAGE
#undef LOADB
#undef MMA
#undef WAITBAR

  // epilogue: C/D layout col=lane&15, row=(lane>>4)*4+reg
#pragma unroll
  for (int rt = 0; rt < 4; rt++) {
#pragma unroll
    for (int ct = 0; ct < 2; ct++) {
#pragma unroll
      for (int i = 0; i < 4; i++) {
        int r = rt * 16 + quad * 4 + i;
        if (r < nrows) {
          int c = colbase + ct * 16 + l16;
          out[(size_t)(rowbase + r) * CB + c] = acc[rt][ct][i];
        }
      }
    }
  }

  if constexpr (STATS) {
    // fused next-BN stats: tail rows contribute exact zeros (masked gathers)
#pragma unroll
    for (int ct = 0; ct < 2; ct++) {
      float s = 0.f, q = 0.f;
#pragma unroll
      for (int rt = 0; rt < 4; rt++)
#pragma unroll
        for (int i = 0; i < 4; i++) { float v = acc[rt][ct][i]; s += v; q += v * v; }
      s += __shfl_xor(s, 16); s += __shfl_xor(s, 32);   // reduce over quad lanes
      q += __shfl_xor(q, 16); q += __shfl_xor(q, 32);
      if (quad == 0) {
        int cch = colbase + ct * 16 + l16;
        atomicAdd(&sums[cch], s);
        atomicAdd(&sums[CB + cch], q);
      }
    }
  }
}

extern "C" void kernel_launch(void* const* d_in, const int* in_sizes, int n_in,
                              void* d_out, int out_size, void* d_ws, size_t ws_size,
                              hipStream_t stream) {
  const float* feat   = (const float*)d_in[0];
  const float* gamma1 = (const float*)d_in[1];
  const float* beta1  = (const float*)d_in[2];
  const float* W1     = (const float*)d_in[3];
  const float* gamma2 = (const float*)d_in[4];
  const float* beta2  = (const float*)d_in[5];
  const float* W2     = (const float*)d_in[6];
  const float* Wnin   = (const float*)d_in[7];
  const int*   nbr    = (const int*)d_in[8];
  const void*  mask   = d_in[9];
  float* out = (float*)d_out;

  const int n = in_sizes[0] / CA;  // 100000

  char* ws = (char*)d_ws;
  size_t off = 0;
  auto alloc = [&](size_t bytes) { size_t p = off; off += (bytes + 255) & ~(size_t)255; return p; };
  int*            flag  = (int*)           (ws + alloc(256));
  char*           zpage = (char*)          (ws + alloc(256));   // 16B+ of zeros for masked DMA
  float*          sums1 = (float*)         (ws + alloc(2 * CA * 4));
  float*          sums2 = (float*)         (ws + alloc(2 * CB * 4));
  float*          sc1   = (float*)         (ws + alloc(2 * CA * 4));
  float*          sc2   = (float*)         (ws + alloc(2 * CB * 4));
  uint32_t*       mbits = (uint32_t*)      (ws + alloc((size_t)n * 4));
  unsigned short* fb    = (unsigned short*)(ws + alloc((size_t)n * CA * 2));
  unsigned short* hb1   = (unsigned short*)(ws + alloc((size_t)n * CA * 2));
  float*          out1  = (float*)         (ws + alloc((size_t)n * CB * 4));
  unsigned short* hb2   = (unsigned short*)(ws + alloc((size_t)n * CB * 2));
  unsigned short* w1t   = (unsigned short*)(ws + alloc((size_t)KOFF * CB * CA * 2));
  unsigned short* w2t   = (unsigned short*)(ws + alloc((size_t)KOFF * CB * CB * 2));
  unsigned short* wnt   = (unsigned short*)(ws + alloc((size_t)CB * CA * 2));

  // zero flag + zpage + stats accumulators (ws is poisoned 0xAA pre-launch)
  hipMemsetAsync(d_ws, 0, 2048, stream);

  detect_mask_k<<<1, 256, 0, stream>>>((const unsigned char*)mask, flag);
  pack_mask_k<<<(n + 255) / 256, 256, 0, stream>>>(mask, flag, mbits, n);

  {
    int tot = KOFF * CA * CB + KOFF * CB * CB + CA * CB;
    transpose_all_k<<<(tot + 255) / 256, 256, 0, stream>>>(W1, W2, Wnin, w1t, w2t, wnt);
  }

  // stage 1: BN stats -> scale/shift -> h1 (bn+relu bf16) + raw feat bf16
  col_stats_k<CA><<<256, 256, 0, stream>>>(feat, n, sums1);
  bn_finalize_k<CA><<<1, CA, 0, stream>>>(sums1, gamma1, beta1, sc1, n);
  bn_apply_k<CA, true><<<(n * CA / 4 + 255) / 256, 256, 0, stream>>>(feat, sc1, hb1, fb, n * CA);

  // conv1: out1 = subconv(h1, W1)  [N,128] fp32, BN2 stats fused in epilogue
  conv_k<CA, false, true><<<(n + 63) / 64, 256, 0, stream>>>(hb1, w1t, nbr, mbits, nullptr, nullptr, zpage, out1, sums2, n);

  // stage 2 (col_stats pass eliminated -- stats came from conv1)
  bn_finalize_k<CB><<<1, CB, 0, stream>>>(sums2, gamma2, beta2, sc2, n);
  bn_apply_k<CB, false><<<(n * CB / 4 + 255) / 256, 256, 0, stream>>>(out1, sc2, hb2, nullptr, n * CB);

  // conv2 + fused NiN shortcut
  conv_k<CB, true, false><<<(n + 63) / 64, 256, 0, stream>>>(hb2, w2t, nbr, mbits, fb, wnt, zpage, out, nullptr, n);
}

// Round 6
// 506.346 us; speedup vs baseline: 1.6823x; 1.0144x over previous
//
#include <hip/hip_runtime.h>
#include <stdint.h>

#define CA 64     // in channels
#define CB 128    // out channels
#define KOFF 27   // 3^3 offsets
#define BN_EPS 1e-4f

typedef short bf16x8 __attribute__((ext_vector_type(8)));
typedef float f32x4 __attribute__((ext_vector_type(4)));
typedef unsigned int u32x4 __attribute__((ext_vector_type(4)));
typedef unsigned short u16x4 __attribute__((ext_vector_type(4)));

__device__ __forceinline__ unsigned short f2bf(float f) {
  union { float f; uint32_t u; } c; c.f = f;
  uint32_t u = c.u;
  return (unsigned short)((u + 0x7FFFu + ((u >> 16) & 1u)) >> 16);  // RNE
}

// ---- mask dtype detection: if int32 layout, bytes at i%4!=0 are all zero ----
__global__ void detect_mask_k(const unsigned char* __restrict__ m, int* flag) {
  unsigned v = 0;
  for (int i = threadIdx.x; i < 4096; i += 256)
    if (i & 3) v |= m[i];
  if (v) atomicOr(flag, 1);   // 1 => byte/bool layout, 0 => int32 layout
}

__global__ void pack_mask_k(const void* __restrict__ mp, const int* __restrict__ flag,
                            uint32_t* __restrict__ bits, int n) {
  int i = blockIdx.x * blockDim.x + threadIdx.x;
  if (i >= n) return;
  uint32_t b = 0;
  if (*flag) {
    const unsigned char* m = (const unsigned char*)mp + (size_t)i * KOFF;
    for (int k = 0; k < KOFF; k++) b |= (m[k] ? 1u : 0u) << k;
  } else {
    const int* m = (const int*)mp + (size_t)i * KOFF;
    for (int k = 0; k < KOFF; k++) b |= (m[k] ? 1u : 0u) << k;
  }
  bits[i] = b;
}

// ---- all weight transposes + bf16 convert in one launch ----
// wt[k][co][ci] = bf16(w[k][ci][co])
__global__ void transpose_all_k(const float* __restrict__ W1, const float* __restrict__ W2,
                                const float* __restrict__ Wnin,
                                unsigned short* __restrict__ w1t, unsigned short* __restrict__ w2t,
                                unsigned short* __restrict__ wnt) {
  const int t1 = KOFF * CA * CB, t2 = KOFF * CB * CB, t3 = CA * CB;
  int idx = blockIdx.x * blockDim.x + threadIdx.x;
  if (idx < t1) {
    int ci = idx % CA; int r = idx / CA; int co = r % CB; int k = r / CB;
    w1t[idx] = f2bf(W1[((size_t)k * CA + ci) * CB + co]);
  } else if (idx < t1 + t2) {
    int j = idx - t1;
    int ci = j % CB; int r = j / CB; int co = r % CB; int k = r / CB;
    w2t[j] = f2bf(W2[((size_t)k * CB + ci) * CB + co]);
  } else if (idx < t1 + t2 + t3) {
    int j = idx - t1 - t2;
    int ci = j % CA; int co = j / CA;
    wnt[j] = f2bf(Wnin[(size_t)ci * CB + co]);
  }
}

// ---- per-channel sum & sumsq (training-mode BN stats) ----
template<int C>
__global__ void col_stats_k(const float* __restrict__ x, int n, float* __restrict__ sums) {
  __shared__ float ssum[C], ssq[C];
  int t = threadIdx.x;
  for (int i = t; i < C; i += 256) { ssum[i] = 0.f; ssq[i] = 0.f; }
  __syncthreads();
  const int c = t % C;
  const int rpb = 256 / C;
  float s = 0.f, q = 0.f;
  for (int r = blockIdx.x * rpb + t / C; r < n; r += gridDim.x * rpb) {
    float v = x[(size_t)r * C + c];
    s += v; q += v * v;
  }
  atomicAdd(&ssum[c], s);
  atomicAdd(&ssq[c], q);
  __syncthreads();
  for (int i = t; i < C; i += 256) {
    atomicAdd(&sums[i], ssum[i]);
    atomicAdd(&sums[C + i], ssq[i]);
  }
}

template<int C>
__global__ void bn_finalize_k(const float* __restrict__ sums, const float* __restrict__ gamma,
                              const float* __restrict__ beta, float* __restrict__ sc, int n) {
  int c = threadIdx.x;
  if (c >= C) return;
  float inv_n = 1.f / (float)n;
  float mean = sums[c] * inv_n;
  float var = sums[C + c] * inv_n - mean * mean;
  float rstd = rsqrtf(var + BN_EPS);
  float scale = gamma[c] * rstd;
  sc[c] = scale;
  sc[C + c] = beta[c] - mean * scale;
}

template<int C, bool RAW>
__global__ void bn_apply_k(const float* __restrict__ x, const float* __restrict__ sc,
                           unsigned short* __restrict__ h, unsigned short* __restrict__ raw,
                           int total) {
  int idx = (blockIdx.x * blockDim.x + threadIdx.x) * 4;
  if (idx >= total) return;
  f32x4 v = *(const f32x4*)&x[idx];
  int c0 = idx % C;
  u16x4 ho, ro;
#pragma unroll
  for (int j = 0; j < 4; j++) {
    float s = sc[c0 + j], b = sc[C + c0 + j];
    float hv = fmaxf(v[j] * s + b, 0.f);
    ho[j] = f2bf(hv);
    if (RAW) ro[j] = f2bf(v[j]);
  }
  *(u16x4*)&h[idx] = ho;
  if (RAW) *(u16x4*)&raw[idx] = ro;
}

// ---- DMA-staged gather-GEMM subconv, 2-iteration-deep pipeline ----
// out[n,:] = sum_k mask[n,k] * hin[nbr[n,k],:] @ W[k]   (+ FUSE: fbraw @ wnt)
// Block: 64 rows x 128 cols, 256 threads (4 waves of 64x32).
// R0-R5 plateau diagnosis: every load completed within the SAME iteration it
// was issued (1-iter cover < gather latency) -> per-k residual stall at the
// barrier, phases serialize. This version gives every load >=1 full spare
// iteration:
//   tile[3] (k mod 3): DMA(k+2) issued at iter k, consumed at iter k+2.
//   nbr 4-deep (slots j mod 3, NB(3) in prologue): >=2 iters old at use, so
//     the compiler's address-dep wait never force-drains a younger DMA.
//   B 2-deep (bfrE/bfrO) loaded at the TOP of iter k for k+1: B(k+1) is OLDER
//     than DMA(k+2), so MMA(k+1)'s B-use vmcnt wait (oldest-first semantics)
//     leaves DMA(k+2) in flight. sched_barrier(0) pins this order.
//   WAITBAR keep = exactly this iter's issues (NP DMA + NP nbr + 2NKS B):
//     drains DMA(k+1) (needed next iter), keeps everything younger in flight.
// LDS = 3 tiles only: 48KB (conv2, 3 blk/CU), 24KB (conv1, 6 blk/CU).
// R4 lesson: gathers issue exactly once per block. R1 lesson: no forced
// min-occupancy (spill). Source-side XOR swizzle as in R5 (verified).
template<int CIN, bool FUSE, bool STATS>
__launch_bounds__(256)
__global__ void conv_k(const unsigned short* __restrict__ hin,
                       const unsigned short* __restrict__ wt,
                       const int* __restrict__ nbr,
                       const uint32_t* __restrict__ mbits,
                       const unsigned short* __restrict__ fbraw,
                       const unsigned short* __restrict__ wnt,
                       const char* __restrict__ zpage,
                       float* __restrict__ out, float* __restrict__ sums, int n) {
  constexpr int TR = 64;
  constexpr int NKS = CIN / 32;     // MFMA K-steps per offset (2 or 4)
  constexpr int CH = CIN / 8;       // 16B chunks per row (8 or 16)
  constexpr int RPP = 256 / CH;     // rows per staging pass (block-wide)
  constexpr int RPW = 64 / CH;      // rows per wave per pass
  constexpr int NP = TR / RPP;      // staging passes (2 or 4)

  __shared__ alignas(16) unsigned short tile[3][TR * CIN];

  const int t = threadIdx.x;
  const int lane = t & 63;
  const int wave = t >> 6;
  const int l16 = lane & 15;
  const int quad = lane >> 4;
  const int colbase = wave * 32;
  const int rowbase = blockIdx.x * TR;
  const int nrows = min(TR, n - rowbase);

  const int c16 = t % CH;           // phys 16B chunk this lane's DMA writes
  const int grow = t / CH;          // row-within-pass
  // source-side swizzle: fetch logical chunk c16^(grow&(CH-1)) -> stored
  // layout identical to the verified conflict-free layout (R3/R5).
  const char* hsrc = (const char*)hin + (c16 ^ (grow & (CH - 1))) * 16;
  const int wvrow = wave * RPW;     // wave-uniform base row within a pass

  uint32_t pm[NP]; int nbro[NP];
#pragma unroll
  for (int p = 0; p < NP; p++) {
    int rg = rowbase + p * RPP + grow;
    pm[p] = (rg < n) ? mbits[rg] : 0u;
    nbro[p] = min(rg, n - 1) * KOFF;  // clamped: masked lanes use zpage anyway
  }

  const int boff0 = (colbase + l16) * CIN + quad * 8;
  const int boff1 = boff0 + 16 * CIN;

  f32x4 acc[4][2];
#pragma unroll
  for (int i = 0; i < 4; i++) { acc[i][0] = f32x4{0,0,0,0}; acc[i][1] = f32x4{0,0,0,0}; }

  bf16x8 bfrE[2 * NKS], bfrO[2 * NKS];  // B slots by k parity
  int nb0[NP], nb1[NP], nb2[NP];        // nbr slots by k mod 3

#define NBLS(kk, nb)                                                           \
  { _Pragma("unroll")                                                          \
    for (int p = 0; p < NP; p++) nb[p] = nbr[nbro[p] + (kk)]; }
#define NBL(kk) do {                                                           \
    if (((kk) % 3) == 0)      NBLS(kk, nb0)                                    \
    else if (((kk) % 3) == 1) NBLS(kk, nb1)                                    \
    else                      NBLS(kk, nb2)                                    \
  } while (0)

#define DMAS(kk, bi, nb)                                                       \
  { _Pragma("unroll")                                                          \
    for (int p = 0; p < NP; p++) {                                             \
      const char* g = ((pm[p] >> (kk)) & 1u)                                   \
          ? hsrc + (size_t)((unsigned)nb[p] * (unsigned)(CIN * 2))             \
          : zpage;                                                             \
      __builtin_amdgcn_global_load_lds(                                        \
          (const __attribute__((address_space(1))) void*)g,                    \
          (__attribute__((address_space(3))) void*)                            \
              &tile[bi][(p * RPP + wvrow) * CIN],                              \
          16, 0, 0);                                                           \
    } }
#define DMAD(kk) do {                                                          \
    if (((kk) % 3) == 0)      DMAS(kk, 0, nb0)                                 \
    else if (((kk) % 3) == 1) DMAS(kk, 1, nb1)                                 \
    else                      DMAS(kk, 2, nb2)                                 \
  } while (0)

#define LOADB(kk, dst)                                                         \
  {                                                                            \
    const unsigned short* wk = wt + (size_t)(kk) * (CB * CIN);                 \
    _Pragma("unroll")                                                          \
    for (int ks = 0; ks < NKS; ks++) {                                         \
      dst[2 * ks]     = *(const bf16x8*)&wk[boff0 + ks * 32];                  \
      dst[2 * ks + 1] = *(const bf16x8*)&wk[boff1 + ks * 32];                  \
    }                                                                          \
  }
#define LOADBD(kk) do {                                                        \
    if (((kk) & 1) == 0) LOADB(kk, bfrE) else LOADB(kk, bfrO)                  \
  } while (0)

#define MMA(bi, bn)                                                            \
  {                                                                            \
    _Pragma("unroll")                                                          \
    for (int ks = 0; ks < NKS; ks++) {                                         \
      _Pragma("unroll")                                                        \
      for (int rt = 0; rt < 4; rt++) {                                         \
        int row = rt * 16 + l16;                                               \
        bf16x8 a = *(const bf16x8*)&tile[bi][row * CIN +                       \
                      (((ks * 4 + quad) ^ (row & (CH - 1))) * 8)];             \
        acc[rt][0] = __builtin_amdgcn_mfma_f32_16x16x32_bf16(a, bn[2 * ks],     acc[rt][0], 0, 0, 0); \
        acc[rt][1] = __builtin_amdgcn_mfma_f32_16x16x32_bf16(a, bn[2 * ks + 1], acc[rt][1], 0, 0, 0); \
      }                                                                        \
    }                                                                          \
  }
#define MMAD(k_) do {                                                          \
    if (((k_) % 3) == 0)      { if (((k_) & 1) == 0) MMA(0, bfrE) else MMA(0, bfrO) } \
    else if (((k_) % 3) == 1) { if (((k_) & 1) == 0) MMA(1, bfrE) else MMA(1, bfrO) } \
    else                      { if (((k_) & 1) == 0) MMA(2, bfrE) else MMA(2, bfrO) } \
  } while (0)

// counted drain + barrier: keep = ops issued THIS iteration (stay in flight),
// everything older (in particular next iter's tile DMA) is forced complete.
#define WAITBAR(keep)                                                          \
  asm volatile("s_waitcnt vmcnt(%0) lgkmcnt(0)\n\ts_barrier"                   \
               :: "i"(keep) : "memory")

  // ---- prologue: nbr 0..3, DMA 0&1, B(0); NiN covers latencies ----
  NBL(0); NBL(1); NBL(2);
  DMAD(0);
  NBL(3);                       // slot 0 regs free (DMA(0) already consumed them)

  if constexpr (FUSE) {
    // NiN shortcut: acc += fbraw @ wnt, straight from global (the 16B A-frag
    // IS a contiguous row chunk); its MFMAs cover the prologue DMA latency.
#pragma unroll
    for (int ks = 0; ks < CA / 32; ks++) {
      bf16x8 b0 = *(const bf16x8*)&wnt[(colbase + l16) * CA + ks * 32 + quad * 8];
      bf16x8 b1 = *(const bf16x8*)&wnt[(colbase + 16 + l16) * CA + ks * 32 + quad * 8];
#pragma unroll
      for (int rt = 0; rt < 4; rt++) {
        int r = rt * 16 + l16;
        bf16x8 a = bf16x8{0, 0, 0, 0, 0, 0, 0, 0};
        if (r < nrows)
          a = *(const bf16x8*)&fbraw[(size_t)(rowbase + r) * CA + ks * 32 + quad * 8];
        acc[rt][0] = __builtin_amdgcn_mfma_f32_16x16x32_bf16(a, b0, acc[rt][0], 0, 0, 0);
        acc[rt][1] = __builtin_amdgcn_mfma_f32_16x16x32_bf16(a, b1, acc[rt][1], 0, 0, 0);
      }
    }
  }

  LOADBD(0);                    // B(0) -> bfrE, older than DMA(1)
  __builtin_amdgcn_sched_barrier(0);
  DMAD(1);
  WAITBAR(NP);                  // keep DMA(1) in flight; tile0/B(0)/nbr drained

  // ---- main loop: FULL unroll, all slot indices compile-time ----
#pragma unroll
  for (int k = 0; k < KOFF; k++) {
    if (k + 1 < KOFF) {
      LOADBD(k + 1);                      // B first: must be OLDER than the DMA
      __builtin_amdgcn_sched_barrier(0);
    }
    if (k + 2 < KOFF) DMAD(k + 2);        // lands at end of iter k+1
    if (k + 4 < KOFF) NBL(k + 4);         // >=2 iters of cover for nbr
    __builtin_amdgcn_sched_barrier(0);
    MMAD(k);
    if (k + 1 < KOFF) {
      WAITBAR(((k + 2 < KOFF) ? NP : 0) + ((k + 4 < KOFF) ? NP : 0) + 2 * NKS);
    }
  }
#undef NBLS
#undef NBL
#undef DMAS
#undef DMAD
#undef LOADB
#undef LOADBD
#undef MMA
#undef MMAD
#undef WAITBAR

  // epilogue: C/D layout col=lane&15, row=(lane>>4)*4+reg
#pragma unroll
  for (int rt = 0; rt < 4; rt++) {
#pragma unroll
    for (int ct = 0; ct < 2; ct++) {
#pragma unroll
      for (int i = 0; i < 4; i++) {
        int r = rt * 16 + quad * 4 + i;
        if (r < nrows) {
          int c = colbase + ct * 16 + l16;
          out[(size_t)(rowbase + r) * CB + c] = acc[rt][ct][i];
        }
      }
    }
  }

  if constexpr (STATS) {
    // fused next-BN stats: tail rows contribute exact zeros (masked gathers)
#pragma unroll
    for (int ct = 0; ct < 2; ct++) {
      float s = 0.f, q = 0.f;
#pragma unroll
      for (int rt = 0; rt < 4; rt++)
#pragma unroll
        for (int i = 0; i < 4; i++) { float v = acc[rt][ct][i]; s += v; q += v * v; }
      s += __shfl_xor(s, 16); s += __shfl_xor(s, 32);   // reduce over quad lanes
      q += __shfl_xor(q, 16); q += __shfl_xor(q, 32);
      if (quad == 0) {
        int cch = colbase + ct * 16 + l16;
        atomicAdd(&sums[cch], s);
        atomicAdd(&sums[CB + cch], q);
      }
    }
  }
}

extern "C" void kernel_launch(void* const* d_in, const int* in_sizes, int n_in,
                              void* d_out, int out_size, void* d_ws, size_t ws_size,
                              hipStream_t stream) {
  const float* feat   = (const float*)d_in[0];
  const float* gamma1 = (const float*)d_in[1];
  const float* beta1  = (const float*)d_in[2];
  const float* W1     = (const float*)d_in[3];
  const float* gamma2 = (const float*)d_in[4];
  const float* beta2  = (const float*)d_in[5];
  const float* W2     = (const float*)d_in[6];
  const float* Wnin   = (const float*)d_in[7];
  const int*   nbr    = (const int*)d_in[8];
  const void*  mask   = d_in[9];
  float* out = (float*)d_out;

  const int n = in_sizes[0] / CA;  // 100000

  char* ws = (char*)d_ws;
  size_t off = 0;
  auto alloc = [&](size_t bytes) { size_t p = off; off += (bytes + 255) & ~(size_t)255; return p; };
  int*            flag  = (int*)           (ws + alloc(256));
  char*           zpage = (char*)          (ws + alloc(256));   // 16B+ of zeros for masked DMA
  float*          sums1 = (float*)         (ws + alloc(2 * CA * 4));
  float*          sums2 = (float*)         (ws + alloc(2 * CB * 4));
  float*          sc1   = (float*)         (ws + alloc(2 * CA * 4));
  float*          sc2   = (float*)         (ws + alloc(2 * CB * 4));
  uint32_t*       mbits = (uint32_t*)      (ws + alloc((size_t)n * 4));
  unsigned short* fb    = (unsigned short*)(ws + alloc((size_t)n * CA * 2));
  unsigned short* hb1   = (unsigned short*)(ws + alloc((size_t)n * CA * 2));
  float*          out1  = (float*)         (ws + alloc((size_t)n * CB * 4));
  unsigned short* hb2   = (unsigned short*)(ws + alloc((size_t)n * CB * 2));
  unsigned short* w1t   = (unsigned short*)(ws + alloc((size_t)KOFF * CB * CA * 2));
  unsigned short* w2t   = (unsigned short*)(ws + alloc((size_t)KOFF * CB * CB * 2));
  unsigned short* wnt   = (unsigned short*)(ws + alloc((size_t)CB * CA * 2));

  // zero flag + zpage + stats accumulators (ws is poisoned 0xAA pre-launch)
  hipMemsetAsync(d_ws, 0, 2048, stream);

  detect_mask_k<<<1, 256, 0, stream>>>((const unsigned char*)mask, flag);
  pack_mask_k<<<(n + 255) / 256, 256, 0, stream>>>(mask, flag, mbits, n);

  {
    int tot = KOFF * CA * CB + KOFF * CB * CB + CA * CB;
    transpose_all_k<<<(tot + 255) / 256, 256, 0, stream>>>(W1, W2, Wnin, w1t, w2t, wnt);
  }

  // stage 1: BN stats -> scale/shift -> h1 (bn+relu bf16) + raw feat bf16
  col_stats_k<CA><<<256, 256, 0, stream>>>(feat, n, sums1);
  bn_finalize_k<CA><<<1, CA, 0, stream>>>(sums1, gamma1, beta1, sc1, n);
  bn_apply_k<CA, true><<<(n * CA / 4 + 255) / 256, 256, 0, stream>>>(feat, sc1, hb1, fb, n * CA);

  // conv1: out1 = subconv(h1, W1)  [N,128] fp32, BN2 stats fused in epilogue
  conv_k<CA, false, true><<<(n + 63) / 64, 256, 0, stream>>>(hb1, w1t, nbr, mbits, nullptr, nullptr, zpage, out1, sums2, n);

  // stage 2 (col_stats pass eliminated -- stats came from conv1)
  bn_finalize_k<CB><<<1, CB, 0, stream>>>(sums2, gamma2, beta2, sc2, n);
  bn_apply_k<CB, false><<<(n * CB / 4 + 255) / 256, 256, 0, stream>>>(out1, sc2, hb2, nullptr, n * CB);

  // conv2 + fused NiN shortcut
  conv_k<CB, true, false><<<(n + 63) / 64, 256, 0, stream>>>(hb2, w2t, nbr, mbits, fb, wnt, zpage, out, nullptr, n);
}

// Round 7
// 504.097 us; speedup vs baseline: 1.6898x; 1.0045x over previous
//
#include <hip/hip_runtime.h>
#include <stdint.h>

#define CA 64     // in channels
#define CB 128    // out channels
#define KOFF 27   // 3^3 offsets
#define BN_EPS 1e-4f

typedef short bf16x8 __attribute__((ext_vector_type(8)));
typedef float f32x4 __attribute__((ext_vector_type(4)));
typedef unsigned int u32x4 __attribute__((ext_vector_type(4)));
typedef unsigned short u16x4 __attribute__((ext_vector_type(4)));

__device__ __forceinline__ unsigned short f2bf(float f) {
  union { float f; uint32_t u; } c; c.f = f;
  uint32_t u = c.u;
  return (unsigned short)((u + 0x7FFFu + ((u >> 16) & 1u)) >> 16);  // RNE
}

// ---- mask dtype detection: if int32 layout, bytes at i%4!=0 are all zero ----
__global__ void detect_mask_k(const unsigned char* __restrict__ m, int* flag) {
  unsigned v = 0;
  for (int i = threadIdx.x; i < 4096; i += 256)
    if (i & 3) v |= m[i];
  if (v) atomicOr(flag, 1);   // 1 => byte/bool layout, 0 => int32 layout
}

__global__ void pack_mask_k(const void* __restrict__ mp, const int* __restrict__ flag,
                            uint32_t* __restrict__ bits, int n) {
  int i = blockIdx.x * blockDim.x + threadIdx.x;
  if (i >= n) return;
  uint32_t b = 0;
  if (*flag) {
    const unsigned char* m = (const unsigned char*)mp + (size_t)i * KOFF;
    for (int k = 0; k < KOFF; k++) b |= (m[k] ? 1u : 0u) << k;
  } else {
    const int* m = (const int*)mp + (size_t)i * KOFF;
    for (int k = 0; k < KOFF; k++) b |= (m[k] ? 1u : 0u) << k;
  }
  bits[i] = b;
}

// ---- all weight transposes + bf16 convert in one launch ----
// wt[k][co][ci] = bf16(w[k][ci][co])
__global__ void transpose_all_k(const float* __restrict__ W1, const float* __restrict__ W2,
                                const float* __restrict__ Wnin,
                                unsigned short* __restrict__ w1t, unsigned short* __restrict__ w2t,
                                unsigned short* __restrict__ wnt) {
  const int t1 = KOFF * CA * CB, t2 = KOFF * CB * CB, t3 = CA * CB;
  int idx = blockIdx.x * blockDim.x + threadIdx.x;
  if (idx < t1) {
    int ci = idx % CA; int r = idx / CA; int co = r % CB; int k = r / CB;
    w1t[idx] = f2bf(W1[((size_t)k * CA + ci) * CB + co]);
  } else if (idx < t1 + t2) {
    int j = idx - t1;
    int ci = j % CB; int r = j / CB; int co = r % CB; int k = r / CB;
    w2t[j] = f2bf(W2[((size_t)k * CB + ci) * CB + co]);
  } else if (idx < t1 + t2 + t3) {
    int j = idx - t1 - t2;
    int ci = j % CA; int co = j / CA;
    wnt[j] = f2bf(Wnin[(size_t)ci * CB + co]);
  }
}

// ---- per-channel sum & sumsq (training-mode BN stats) ----
template<int C>
__global__ void col_stats_k(const float* __restrict__ x, int n, float* __restrict__ sums) {
  __shared__ float ssum[C], ssq[C];
  int t = threadIdx.x;
  for (int i = t; i < C; i += 256) { ssum[i] = 0.f; ssq[i] = 0.f; }
  __syncthreads();
  const int c = t % C;
  const int rpb = 256 / C;
  float s = 0.f, q = 0.f;
  for (int r = blockIdx.x * rpb + t / C; r < n; r += gridDim.x * rpb) {
    float v = x[(size_t)r * C + c];
    s += v; q += v * v;
  }
  atomicAdd(&ssum[c], s);
  atomicAdd(&ssq[c], q);
  __syncthreads();
  for (int i = t; i < C; i += 256) {
    atomicAdd(&sums[i], ssum[i]);
    atomicAdd(&sums[C + i], ssq[i]);
  }
}

template<int C>
__global__ void bn_finalize_k(const float* __restrict__ sums, const float* __restrict__ gamma,
                              const float* __restrict__ beta, float* __restrict__ sc, int n) {
  int c = threadIdx.x;
  if (c >= C) return;
  float inv_n = 1.f / (float)n;
  float mean = sums[c] * inv_n;
  float var = sums[C + c] * inv_n - mean * mean;
  float rstd = rsqrtf(var + BN_EPS);
  float scale = gamma[c] * rstd;
  sc[c] = scale;
  sc[C + c] = beta[c] - mean * scale;
}

template<int C, bool RAW>
__global__ void bn_apply_k(const float* __restrict__ x, const float* __restrict__ sc,
                           unsigned short* __restrict__ h, unsigned short* __restrict__ raw,
                           int total) {
  int idx = (blockIdx.x * blockDim.x + threadIdx.x) * 4;
  if (idx >= total) return;
  f32x4 v = *(const f32x4*)&x[idx];
  int c0 = idx % C;
  u16x4 ho, ro;
#pragma unroll
  for (int j = 0; j < 4; j++) {
    float s = sc[c0 + j], b = sc[C + c0 + j];
    float hv = fmaxf(v[j] * s + b, 0.f);
    ho[j] = f2bf(hv);
    if (RAW) ro[j] = f2bf(v[j]);
  }
  *(u16x4*)&h[idx] = ho;
  if (RAW) *(u16x4*)&raw[idx] = ro;
}

// ---- DMA-staged gather-GEMM subconv, 8-wave column-split ----
// out[n,:] = sum_k mask[n,k] * hin[nbr[n,k],:] @ W[k]   (+ FUSE: fbraw @ wnt)
// Block: 64 rows x 128 cols, 512 threads = 8 waves; wave w owns 16 cols.
// R0-R6 invariant diagnosis: all pipes <=30% busy, dur pinned 215-235us across
// staging/pipelining/conflict variants -> wave-concurrency bound (4-wave
// blocks, ~8 active waves/CU). This keeps per-BLOCK totals identical (MFMA,
// gather/B/nbr instruction counts -- gathers once per block, R4 lesson) but
// doubles waves/CU and halves per-wave chain length: LDS 32KB (2x16KB dbuf)
// -> 4 blocks x 8 waves = up to 32 waves/CU. Only cost: 2x LDS read traffic.
// Staging via global_load_lds DMA, source-side XOR swizzle (verified R5/R6),
// zpage for masked rows, counted-vmcnt WAITBAR, full unroll, parity-static
// register slots. No forced min-occupancy (R1 spill lesson).
template<int CIN, bool FUSE, bool STATS>
__launch_bounds__(512)
__global__ void conv_k(const unsigned short* __restrict__ hin,
                       const unsigned short* __restrict__ wt,
                       const int* __restrict__ nbr,
                       const uint32_t* __restrict__ mbits,
                       const unsigned short* __restrict__ fbraw,
                       const unsigned short* __restrict__ wnt,
                       const char* __restrict__ zpage,
                       float* __restrict__ out, float* __restrict__ sums, int n) {
  constexpr int TR = 64;
  constexpr int NKS = CIN / 32;     // MFMA K-steps per offset (2 or 4)
  constexpr int CH = CIN / 8;       // 16B chunks per row (8 or 16)
  constexpr int RPP = 512 / CH;     // rows per staging pass (block-wide)
  constexpr int RPW = 64 / CH;      // rows per wave per pass
  constexpr int NP = TR / RPP;      // staging passes (1 or 2)

  __shared__ alignas(16) unsigned short tile[2][TR * CIN];

  const int t = threadIdx.x;
  const int lane = t & 63;
  const int wave = t >> 6;
  const int l16 = lane & 15;
  const int quad = lane >> 4;
  const int colbase = wave * 16;    // 8 waves x 16 cols = 128
  const int rowbase = blockIdx.x * TR;
  const int nrows = min(TR, n - rowbase);

  const int c16 = t % CH;           // phys 16B chunk this lane's DMA writes
  const int grow = t / CH;          // row-within-pass (= wave*RPW + lane/CH)
  // source-side swizzle: fetch logical chunk c16^(grow&(CH-1)) -> stored
  // layout identical to the verified conflict-free layout (R3/R5/R6).
  // (RPP is a multiple of CH, so row&(CH-1) == grow&(CH-1) for all passes.)
  const char* hsrc = (const char*)hin + (c16 ^ (grow & (CH - 1))) * 16;
  const int wvrow = wave * RPW;     // wave-uniform base row within a pass

  uint32_t pm[NP]; int nbro[NP];
#pragma unroll
  for (int p = 0; p < NP; p++) {
    int rg = rowbase + p * RPP + grow;
    pm[p] = (rg < n) ? mbits[rg] : 0u;
    nbro[p] = min(rg, n - 1) * KOFF;  // clamped: masked lanes use zpage anyway
  }

  const int boff = (colbase + l16) * CIN + quad * 8;

  f32x4 acc[4];
#pragma unroll
  for (int i = 0; i < 4; i++) acc[i] = f32x4{0, 0, 0, 0};

  bf16x8 bfrE[NKS], bfrO[NKS];  // B slots by k parity (16-col tile each)
  int nbE[NP], nbO[NP];         // nbr slots by k parity (static indexing)

#define NBLOAD(kk, nb)                                                         \
  { _Pragma("unroll")                                                          \
    for (int p = 0; p < NP; p++) nb[p] = nbr[nbro[p] + (kk)]; }

#define DMASTAGE(kk, buf, nb)                                                  \
  { _Pragma("unroll")                                                          \
    for (int p = 0; p < NP; p++) {                                             \
      const char* g = ((pm[p] >> (kk)) & 1u)                                   \
          ? hsrc + (size_t)((unsigned)nb[p] * (unsigned)(CIN * 2))             \
          : zpage;                                                             \
      __builtin_amdgcn_global_load_lds(                                        \
          (const __attribute__((address_space(1))) void*)g,                    \
          (__attribute__((address_space(3))) void*)                            \
              &tile[buf][(p * RPP + wvrow) * CIN],                             \
          16, 0, 0);                                                           \
    } }

#define LOADB(kk, dst)                                                         \
  {                                                                            \
    const unsigned short* wk = wt + (size_t)(kk) * (CB * CIN);                 \
    _Pragma("unroll")                                                          \
    for (int ks = 0; ks < NKS; ks++)                                           \
      dst[ks] = *(const bf16x8*)&wk[boff + ks * 32];                           \
  }

#define MMA(buf, bn)                                                           \
  {                                                                            \
    _Pragma("unroll")                                                          \
    for (int ks = 0; ks < NKS; ks++) {                                         \
      _Pragma("unroll")                                                        \
      for (int rt = 0; rt < 4; rt++) {                                         \
        int row = rt * 16 + l16;                                               \
        bf16x8 a = *(const bf16x8*)&tile[buf][row * CIN +                      \
                      (((ks * 4 + quad) ^ (row & (CH - 1))) * 8)];             \
        acc[rt] = __builtin_amdgcn_mfma_f32_16x16x32_bf16(a, bn[ks], acc[rt], 0, 0, 0); \
      }                                                                        \
    }                                                                          \
  }

// counted drain + barrier: keeps exactly the NKS B-loads issued this
// iteration in flight; drains this iteration's DMA + nbr loads.
#define WAITBAR()                                                              \
  asm volatile("s_waitcnt vmcnt(%0) lgkmcnt(0)\n\ts_barrier"                   \
               :: "i"(NKS) : "memory")

  // ---- prologue ----
  NBLOAD(0, nbE);               // addr dependency forces its own wait
  DMASTAGE(0, 0, nbE);
  NBLOAD(1, nbO);
  __builtin_amdgcn_sched_barrier(0);   // nothing hoists above the DMA

  if constexpr (FUSE) {
    // NiN shortcut: acc += fbraw @ wnt, straight from global (the 16B A-frag
    // IS a contiguous row chunk); its MFMAs cover the prologue DMA latency.
#pragma unroll
    for (int ks = 0; ks < CA / 32; ks++) {
      bf16x8 b = *(const bf16x8*)&wnt[(colbase + l16) * CA + ks * 32 + quad * 8];
#pragma unroll
      for (int rt = 0; rt < 4; rt++) {
        int r = rt * 16 + l16;
        bf16x8 a = bf16x8{0, 0, 0, 0, 0, 0, 0, 0};
        if (r < nrows)
          a = *(const bf16x8*)&fbraw[(size_t)(rowbase + r) * CA + ks * 32 + quad * 8];
        acc[rt] = __builtin_amdgcn_mfma_f32_16x16x32_bf16(a, b, acc[rt], 0, 0, 0);
      }
    }
  }

  LOADB(0, bfrE);
  WAITBAR();                    // tile[0] resident; B(0) stays in flight

  // ---- main loop: FULL unroll, parity-static register slots ----
#pragma unroll
  for (int k = 0; k < KOFF; k++) {
    const int cur = k & 1, nxt = cur ^ 1;
    if (k + 1 < KOFF) {
      if (((k + 1) & 1) == 0) DMASTAGE(k + 1, nxt, nbE) else DMASTAGE(k + 1, nxt, nbO);
      if (k + 2 < KOFF) {
        if (((k + 2) & 1) == 0) NBLOAD(k + 2, nbE) else NBLOAD(k + 2, nbO);
      }
      __builtin_amdgcn_sched_barrier(0);  // keep B-loads below the DMA
    }
    if ((k & 1) == 0) MMA(0, bfrE) else MMA(1, bfrO);
    if (k + 1 < KOFF) {
      if (((k + 1) & 1) == 0) LOADB(k + 1, bfrE) else LOADB(k + 1, bfrO);
      WAITBAR();
    }
  }
#undef NBLOAD
#undef DMASTAGE
#undef LOADB
#undef MMA
#undef WAITBAR

  // epilogue: C/D layout col=lane&15, row=(lane>>4)*4+reg
#pragma unroll
  for (int rt = 0; rt < 4; rt++) {
#pragma unroll
    for (int i = 0; i < 4; i++) {
      int r = rt * 16 + quad * 4 + i;
      if (r < nrows) {
        int c = colbase + l16;
        out[(size_t)(rowbase + r) * CB + c] = acc[rt][i];
      }
    }
  }

  if constexpr (STATS) {
    // fused next-BN stats: tail rows contribute exact zeros (masked gathers)
    float s = 0.f, q = 0.f;
#pragma unroll
    for (int rt = 0; rt < 4; rt++)
#pragma unroll
      for (int i = 0; i < 4; i++) { float v = acc[rt][i]; s += v; q += v * v; }
    s += __shfl_xor(s, 16); s += __shfl_xor(s, 32);   // reduce over quad lanes
    q += __shfl_xor(q, 16); q += __shfl_xor(q, 32);
    if (quad == 0) {
      int cch = colbase + l16;
      atomicAdd(&sums[cch], s);
      atomicAdd(&sums[CB + cch], q);
    }
  }
}

extern "C" void kernel_launch(void* const* d_in, const int* in_sizes, int n_in,
                              void* d_out, int out_size, void* d_ws, size_t ws_size,
                              hipStream_t stream) {
  const float* feat   = (const float*)d_in[0];
  const float* gamma1 = (const float*)d_in[1];
  const float* beta1  = (const float*)d_in[2];
  const float* W1     = (const float*)d_in[3];
  const float* gamma2 = (const float*)d_in[4];
  const float* beta2  = (const float*)d_in[5];
  const float* W2     = (const float*)d_in[6];
  const float* Wnin   = (const float*)d_in[7];
  const int*   nbr    = (const int*)d_in[8];
  const void*  mask   = d_in[9];
  float* out = (float*)d_out;

  const int n = in_sizes[0] / CA;  // 100000

  char* ws = (char*)d_ws;
  size_t off = 0;
  auto alloc = [&](size_t bytes) { size_t p = off; off += (bytes + 255) & ~(size_t)255; return p; };
  int*            flag  = (int*)           (ws + alloc(256));
  char*           zpage = (char*)          (ws + alloc(256));   // 16B+ of zeros for masked DMA
  float*          sums1 = (float*)         (ws + alloc(2 * CA * 4));
  float*          sums2 = (float*)         (ws + alloc(2 * CB * 4));
  float*          sc1   = (float*)         (ws + alloc(2 * CA * 4));
  float*          sc2   = (float*)         (ws + alloc(2 * CB * 4));
  uint32_t*       mbits = (uint32_t*)      (ws + alloc((size_t)n * 4));
  unsigned short* fb    = (unsigned short*)(ws + alloc((size_t)n * CA * 2));
  unsigned short* hb1   = (unsigned short*)(ws + alloc((size_t)n * CA * 2));
  float*          out1  = (float*)         (ws + alloc((size_t)n * CB * 4));
  unsigned short* hb2   = (unsigned short*)(ws + alloc((size_t)n * CB * 2));
  unsigned short* w1t   = (unsigned short*)(ws + alloc((size_t)KOFF * CB * CA * 2));
  unsigned short* w2t   = (unsigned short*)(ws + alloc((size_t)KOFF * CB * CB * 2));
  unsigned short* wnt   = (unsigned short*)(ws + alloc((size_t)CB * CA * 2));

  // zero flag + zpage + stats accumulators (ws is poisoned 0xAA pre-launch)
  hipMemsetAsync(d_ws, 0, 2048, stream);

  detect_mask_k<<<1, 256, 0, stream>>>((const unsigned char*)mask, flag);
  pack_mask_k<<<(n + 255) / 256, 256, 0, stream>>>(mask, flag, mbits, n);

  {
    int tot = KOFF * CA * CB + KOFF * CB * CB + CA * CB;
    transpose_all_k<<<(tot + 255) / 256, 256, 0, stream>>>(W1, W2, Wnin, w1t, w2t, wnt);
  }

  // stage 1: BN stats -> scale/shift -> h1 (bn+relu bf16) + raw feat bf16
  col_stats_k<CA><<<256, 256, 0, stream>>>(feat, n, sums1);
  bn_finalize_k<CA><<<1, CA, 0, stream>>>(sums1, gamma1, beta1, sc1, n);
  bn_apply_k<CA, true><<<(n * CA / 4 + 255) / 256, 256, 0, stream>>>(feat, sc1, hb1, fb, n * CA);

  // conv1: out1 = subconv(h1, W1)  [N,128] fp32, BN2 stats fused in epilogue
  conv_k<CA, false, true><<<(n + 63) / 64, 512, 0, stream>>>(hb1, w1t, nbr, mbits, nullptr, nullptr, zpage, out1, sums2, n);

  // stage 2 (col_stats pass eliminated -- stats came from conv1)
  bn_finalize_k<CB><<<1, CB, 0, stream>>>(sums2, gamma2, beta2, sc2, n);
  bn_apply_k<CB, false><<<(n * CB / 4 + 255) / 256, 256, 0, stream>>>(out1, sc2, hb2, nullptr, n * CB);

  // conv2 + fused NiN shortcut
  conv_k<CB, true, false><<<(n + 63) / 64, 512, 0, stream>>>(hb2, w2t, nbr, mbits, fb, wnt, zpage, out, nullptr, n);
}

// Round 8
// 497.267 us; speedup vs baseline: 1.7130x; 1.0137x over previous
//
#include <hip/hip_runtime.h>
#include <stdint.h>

#define CA 64     // in channels
#define CB 128    // out channels
#define KOFF 27   // 3^3 offsets
#define BN_EPS 1e-4f

typedef short bf16x8 __attribute__((ext_vector_type(8)));
typedef float f32x4 __attribute__((ext_vector_type(4)));
typedef unsigned int u32x4 __attribute__((ext_vector_type(4)));
typedef unsigned short u16x4 __attribute__((ext_vector_type(4)));

__device__ __forceinline__ unsigned short f2bf(float f) {
  union { float f; uint32_t u; } c; c.f = f;
  uint32_t u = c.u;
  return (unsigned short)((u + 0x7FFFu + ((u >> 16) & 1u)) >> 16);  // RNE
}

// ---- mask dtype detection: if int32 layout, bytes at i%4!=0 are all zero ----
__global__ void detect_mask_k(const unsigned char* __restrict__ m, int* flag) {
  unsigned v = 0;
  for (int i = threadIdx.x; i < 4096; i += 256)
    if (i & 3) v |= m[i];
  if (v) atomicOr(flag, 1);   // 1 => byte/bool layout, 0 => int32 layout
}

__global__ void pack_mask_k(const void* __restrict__ mp, const int* __restrict__ flag,
                            uint32_t* __restrict__ bits, int n) {
  int i = blockIdx.x * blockDim.x + threadIdx.x;
  if (i >= n) return;
  uint32_t b = 0;
  if (*flag) {
    const unsigned char* m = (const unsigned char*)mp + (size_t)i * KOFF;
    for (int k = 0; k < KOFF; k++) b |= (m[k] ? 1u : 0u) << k;
  } else {
    const int* m = (const int*)mp + (size_t)i * KOFF;
    for (int k = 0; k < KOFF; k++) b |= (m[k] ? 1u : 0u) << k;
  }
  bits[i] = b;
}

// ---- all weight transposes + bf16 convert in one launch ----
// wt[k][co][ci] = bf16(w[k][ci][co])
__global__ void transpose_all_k(const float* __restrict__ W1, const float* __restrict__ W2,
                                const float* __restrict__ Wnin,
                                unsigned short* __restrict__ w1t, unsigned short* __restrict__ w2t,
                                unsigned short* __restrict__ wnt) {
  const int t1 = KOFF * CA * CB, t2 = KOFF * CB * CB, t3 = CA * CB;
  int idx = blockIdx.x * blockDim.x + threadIdx.x;
  if (idx < t1) {
    int ci = idx % CA; int r = idx / CA; int co = r % CB; int k = r / CB;
    w1t[idx] = f2bf(W1[((size_t)k * CA + ci) * CB + co]);
  } else if (idx < t1 + t2) {
    int j = idx - t1;
    int ci = j % CB; int r = j / CB; int co = r % CB; int k = r / CB;
    w2t[j] = f2bf(W2[((size_t)k * CB + ci) * CB + co]);
  } else if (idx < t1 + t2 + t3) {
    int j = idx - t1 - t2;
    int ci = j % CA; int co = j / CA;
    wnt[j] = f2bf(Wnin[(size_t)ci * CB + co]);
  }
}

// ---- per-channel sum & sumsq (training-mode BN stats) ----
template<int C>
__global__ void col_stats_k(const float* __restrict__ x, int n, float* __restrict__ sums) {
  __shared__ float ssum[C], ssq[C];
  int t = threadIdx.x;
  for (int i = t; i < C; i += 256) { ssum[i] = 0.f; ssq[i] = 0.f; }
  __syncthreads();
  const int c = t % C;
  const int rpb = 256 / C;
  float s = 0.f, q = 0.f;
  for (int r = blockIdx.x * rpb + t / C; r < n; r += gridDim.x * rpb) {
    float v = x[(size_t)r * C + c];
    s += v; q += v * v;
  }
  atomicAdd(&ssum[c], s);
  atomicAdd(&ssq[c], q);
  __syncthreads();
  for (int i = t; i < C; i += 256) {
    atomicAdd(&sums[i], ssum[i]);
    atomicAdd(&sums[C + i], ssq[i]);
  }
}

template<int C>
__global__ void bn_finalize_k(const float* __restrict__ sums, const float* __restrict__ gamma,
                              const float* __restrict__ beta, float* __restrict__ sc, int n) {
  int c = threadIdx.x;
  if (c >= C) return;
  float inv_n = 1.f / (float)n;
  float mean = sums[c] * inv_n;
  float var = sums[C + c] * inv_n - mean * mean;
  float rstd = rsqrtf(var + BN_EPS);
  float scale = gamma[c] * rstd;
  sc[c] = scale;
  sc[C + c] = beta[c] - mean * scale;
}

template<int C, bool RAW>
__global__ void bn_apply_k(const float* __restrict__ x, const float* __restrict__ sc,
                           unsigned short* __restrict__ h, unsigned short* __restrict__ raw,
                           int total) {
  int idx = (blockIdx.x * blockDim.x + threadIdx.x) * 4;
  if (idx >= total) return;
  f32x4 v = *(const f32x4*)&x[idx];
  int c0 = idx % C;
  u16x4 ho, ro;
#pragma unroll
  for (int j = 0; j < 4; j++) {
    float s = sc[c0 + j], b = sc[C + c0 + j];
    float hv = fmaxf(v[j] * s + b, 0.f);
    ho[j] = f2bf(hv);
    if (RAW) ro[j] = f2bf(v[j]);
  }
  *(u16x4*)&h[idx] = ho;
  if (RAW) *(u16x4*)&raw[idx] = ro;
}

// ---- DMA-staged gather-GEMM subconv, TR=128 rows/block ----
// out[n,:] = sum_k mask[n,k] * hin[nbr[n,k],:] @ W[k]   (+ FUSE: fbraw @ wnt)
// Block: 128 rows x 128 cols, 512 threads = 8 waves; wave w owns 16 cols.
// R0-R7 diagnosis: dur invariant ~215-235us across staging mechanism, bank
// conflicts, pipeline depth (R6: true 1.5-iter cover), occupancy (R7: 27->37%
// with zero dur change), spills -- and conv1 ~= conv2 despite 2x work ratio.
// => cost is FIXED per (block x k-iteration), not per unit work. This round
// halves the (block x iteration) count: TR 64->128 (782 blocks), doubling
// work per iteration to fill the dead time. Everything else identical to R7.
// LDS = 64KB dbuf (conv2) / 32KB (conv1) -> 2 blocks/CU: safe, R7 proved
// occupancy-insensitivity. Staging via global_load_lds DMA, source-side XOR
// swizzle (verified R5-R7), zpage for masked rows, counted-vmcnt WAITBAR,
// full unroll, parity-static register slots. Gathers once per block (R4
// lesson); no forced min-occupancy (R1 spill lesson).
template<int CIN, bool FUSE, bool STATS>
__launch_bounds__(512)
__global__ void conv_k(const unsigned short* __restrict__ hin,
                       const unsigned short* __restrict__ wt,
                       const int* __restrict__ nbr,
                       const uint32_t* __restrict__ mbits,
                       const unsigned short* __restrict__ fbraw,
                       const unsigned short* __restrict__ wnt,
                       const char* __restrict__ zpage,
                       float* __restrict__ out, float* __restrict__ sums, int n) {
  constexpr int TR = 128;
  constexpr int RT = TR / 16;       // 8 row-tiles per wave
  constexpr int NKS = CIN / 32;     // MFMA K-steps per offset (2 or 4)
  constexpr int CH = CIN / 8;       // 16B chunks per row (8 or 16)
  constexpr int RPP = 512 / CH;     // rows per staging pass (block-wide)
  constexpr int RPW = 64 / CH;      // rows per wave per pass
  constexpr int NP = TR / RPP;      // staging passes (2 or 4)

  __shared__ alignas(16) unsigned short tile[2][TR * CIN];

  const int t = threadIdx.x;
  const int lane = t & 63;
  const int wave = t >> 6;
  const int l16 = lane & 15;
  const int quad = lane >> 4;
  const int colbase = wave * 16;    // 8 waves x 16 cols = 128
  const int rowbase = blockIdx.x * TR;
  const int nrows = min(TR, n - rowbase);

  const int c16 = t % CH;           // phys 16B chunk this lane's DMA writes
  const int grow = t / CH;          // row-within-pass (= wave*RPW + lane/CH)
  // source-side swizzle: fetch logical chunk c16^(grow&(CH-1)) -> stored
  // layout identical to the verified conflict-free layout (R3/R5/R6/R7).
  // (RPP is a multiple of CH, so row&(CH-1) == grow&(CH-1) for all passes.)
  const char* hsrc = (const char*)hin + (c16 ^ (grow & (CH - 1))) * 16;
  const int wvrow = wave * RPW;     // wave-uniform base row within a pass

  uint32_t pm[NP]; int nbro[NP];
#pragma unroll
  for (int p = 0; p < NP; p++) {
    int rg = rowbase + p * RPP + grow;
    pm[p] = (rg < n) ? mbits[rg] : 0u;
    nbro[p] = min(rg, n - 1) * KOFF;  // clamped: masked lanes use zpage anyway
  }

  const int boff = (colbase + l16) * CIN + quad * 8;

  f32x4 acc[RT];
#pragma unroll
  for (int i = 0; i < RT; i++) acc[i] = f32x4{0, 0, 0, 0};

  bf16x8 bfrE[NKS], bfrO[NKS];  // B slots by k parity (16-col tile each)
  int nbE[NP], nbO[NP];         // nbr slots by k parity (static indexing)

#define NBLOAD(kk, nb)                                                         \
  { _Pragma("unroll")                                                          \
    for (int p = 0; p < NP; p++) nb[p] = nbr[nbro[p] + (kk)]; }

#define DMASTAGE(kk, buf, nb)                                                  \
  { _Pragma("unroll")                                                          \
    for (int p = 0; p < NP; p++) {                                             \
      const char* g = ((pm[p] >> (kk)) & 1u)                                   \
          ? hsrc + (size_t)((unsigned)nb[p] * (unsigned)(CIN * 2))             \
          : zpage;                                                             \
      __builtin_amdgcn_global_load_lds(                                        \
          (const __attribute__((address_space(1))) void*)g,                    \
          (__attribute__((address_space(3))) void*)                            \
              &tile[buf][(p * RPP + wvrow) * CIN],                             \
          16, 0, 0);                                                           \
    } }

#define LOADB(kk, dst)                                                         \
  {                                                                            \
    const unsigned short* wk = wt + (size_t)(kk) * (CB * CIN);                 \
    _Pragma("unroll")                                                          \
    for (int ks = 0; ks < NKS; ks++)                                           \
      dst[ks] = *(const bf16x8*)&wk[boff + ks * 32];                           \
  }

#define MMA(buf, bn)                                                           \
  {                                                                            \
    _Pragma("unroll")                                                          \
    for (int ks = 0; ks < NKS; ks++) {                                         \
      _Pragma("unroll")                                                        \
      for (int rt = 0; rt < RT; rt++) {                                        \
        int row = rt * 16 + l16;                                               \
        bf16x8 a = *(const bf16x8*)&tile[buf][row * CIN +                      \
                      (((ks * 4 + quad) ^ (row & (CH - 1))) * 8)];             \
        acc[rt] = __builtin_amdgcn_mfma_f32_16x16x32_bf16(a, bn[ks], acc[rt], 0, 0, 0); \
      }                                                                        \
    }                                                                          \
  }

// counted drain + barrier: keeps exactly the NKS B-loads issued this
// iteration in flight; drains this iteration's DMA + nbr loads.
#define WAITBAR()                                                              \
  asm volatile("s_waitcnt vmcnt(%0) lgkmcnt(0)\n\ts_barrier"                   \
               :: "i"(NKS) : "memory")

  // ---- prologue ----
  NBLOAD(0, nbE);               // addr dependency forces its own wait
  DMASTAGE(0, 0, nbE);
  NBLOAD(1, nbO);
  __builtin_amdgcn_sched_barrier(0);   // nothing hoists above the DMA

  if constexpr (FUSE) {
    // NiN shortcut: acc += fbraw @ wnt, straight from global (the 16B A-frag
    // IS a contiguous row chunk); its MFMAs cover the prologue DMA latency.
#pragma unroll
    for (int ks = 0; ks < CA / 32; ks++) {
      bf16x8 b = *(const bf16x8*)&wnt[(colbase + l16) * CA + ks * 32 + quad * 8];
#pragma unroll
      for (int rt = 0; rt < RT; rt++) {
        int r = rt * 16 + l16;
        bf16x8 a = bf16x8{0, 0, 0, 0, 0, 0, 0, 0};
        if (r < nrows)
          a = *(const bf16x8*)&fbraw[(size_t)(rowbase + r) * CA + ks * 32 + quad * 8];
        acc[rt] = __builtin_amdgcn_mfma_f32_16x16x32_bf16(a, b, acc[rt], 0, 0, 0);
      }
    }
  }

  LOADB(0, bfrE);
  WAITBAR();                    // tile[0] resident; B(0) stays in flight

  // ---- main loop: FULL unroll, parity-static register slots ----
#pragma unroll
  for (int k = 0; k < KOFF; k++) {
    const int cur = k & 1, nxt = cur ^ 1;
    (void)cur;
    if (k + 1 < KOFF) {
      if (((k + 1) & 1) == 0) DMASTAGE(k + 1, nxt, nbE) else DMASTAGE(k + 1, nxt, nbO);
      if (k + 2 < KOFF) {
        if (((k + 2) & 1) == 0) NBLOAD(k + 2, nbE) else NBLOAD(k + 2, nbO);
      }
      __builtin_amdgcn_sched_barrier(0);  // keep B-loads below the DMA
    }
    if ((k & 1) == 0) MMA(0, bfrE) else MMA(1, bfrO);
    if (k + 1 < KOFF) {
      if (((k + 1) & 1) == 0) LOADB(k + 1, bfrE) else LOADB(k + 1, bfrO);
      WAITBAR();
    }
  }
#undef NBLOAD
#undef DMASTAGE
#undef LOADB
#undef MMA
#undef WAITBAR

  // epilogue: C/D layout col=lane&15, row=(lane>>4)*4+reg
#pragma unroll
  for (int rt = 0; rt < RT; rt++) {
#pragma unroll
    for (int i = 0; i < 4; i++) {
      int r = rt * 16 + quad * 4 + i;
      if (r < nrows) {
        int c = colbase + l16;
        out[(size_t)(rowbase + r) * CB + c] = acc[rt][i];
      }
    }
  }

  if constexpr (STATS) {
    // fused next-BN stats: tail rows contribute exact zeros (masked gathers)
    float s = 0.f, q = 0.f;
#pragma unroll
    for (int rt = 0; rt < RT; rt++)
#pragma unroll
      for (int i = 0; i < 4; i++) { float v = acc[rt][i]; s += v; q += v * v; }
    s += __shfl_xor(s, 16); s += __shfl_xor(s, 32);   // reduce over quad lanes
    q += __shfl_xor(q, 16); q += __shfl_xor(q, 32);
    if (quad == 0) {
      int cch = colbase + l16;
      atomicAdd(&sums[cch], s);
      atomicAdd(&sums[CB + cch], q);
    }
  }
}

extern "C" void kernel_launch(void* const* d_in, const int* in_sizes, int n_in,
                              void* d_out, int out_size, void* d_ws, size_t ws_size,
                              hipStream_t stream) {
  const float* feat   = (const float*)d_in[0];
  const float* gamma1 = (const float*)d_in[1];
  const float* beta1  = (const float*)d_in[2];
  const float* W1     = (const float*)d_in[3];
  const float* gamma2 = (const float*)d_in[4];
  const float* beta2  = (const float*)d_in[5];
  const float* W2     = (const float*)d_in[6];
  const float* Wnin   = (const float*)d_in[7];
  const int*   nbr    = (const int*)d_in[8];
  const void*  mask   = d_in[9];
  float* out = (float*)d_out;

  const int n = in_sizes[0] / CA;  // 100000

  char* ws = (char*)d_ws;
  size_t off = 0;
  auto alloc = [&](size_t bytes) { size_t p = off; off += (bytes + 255) & ~(size_t)255; return p; };
  int*            flag  = (int*)           (ws + alloc(256));
  char*           zpage = (char*)          (ws + alloc(256));   // 16B+ of zeros for masked DMA
  float*          sums1 = (float*)         (ws + alloc(2 * CA * 4));
  float*          sums2 = (float*)         (ws + alloc(2 * CB * 4));
  float*          sc1   = (float*)         (ws + alloc(2 * CA * 4));
  float*          sc2   = (float*)         (ws + alloc(2 * CB * 4));
  uint32_t*       mbits = (uint32_t*)      (ws + alloc((size_t)n * 4));
  unsigned short* fb    = (unsigned short*)(ws + alloc((size_t)n * CA * 2));
  unsigned short* hb1   = (unsigned short*)(ws + alloc((size_t)n * CA * 2));
  float*          out1  = (float*)         (ws + alloc((size_t)n * CB * 4));
  unsigned short* hb2   = (unsigned short*)(ws + alloc((size_t)n * CB * 2));
  unsigned short* w1t   = (unsigned short*)(ws + alloc((size_t)KOFF * CB * CA * 2));
  unsigned short* w2t   = (unsigned short*)(ws + alloc((size_t)KOFF * CB * CB * 2));
  unsigned short* wnt   = (unsigned short*)(ws + alloc((size_t)CB * CA * 2));

  // zero flag + zpage + stats accumulators (ws is poisoned 0xAA pre-launch)
  hipMemsetAsync(d_ws, 0, 2048, stream);

  detect_mask_k<<<1, 256, 0, stream>>>((const unsigned char*)mask, flag);
  pack_mask_k<<<(n + 255) / 256, 256, 0, stream>>>(mask, flag, mbits, n);

  {
    int tot = KOFF * CA * CB + KOFF * CB * CB + CA * CB;
    transpose_all_k<<<(tot + 255) / 256, 256, 0, stream>>>(W1, W2, Wnin, w1t, w2t, wnt);
  }

  // stage 1: BN stats -> scale/shift -> h1 (bn+relu bf16) + raw feat bf16
  col_stats_k<CA><<<256, 256, 0, stream>>>(feat, n, sums1);
  bn_finalize_k<CA><<<1, CA, 0, stream>>>(sums1, gamma1, beta1, sc1, n);
  bn_apply_k<CA, true><<<(n * CA / 4 + 255) / 256, 256, 0, stream>>>(feat, sc1, hb1, fb, n * CA);

  // conv1: out1 = subconv(h1, W1)  [N,128] fp32, BN2 stats fused in epilogue
  conv_k<CA, false, true><<<(n + 127) / 128, 512, 0, stream>>>(hb1, w1t, nbr, mbits, nullptr, nullptr, zpage, out1, sums2, n);

  // stage 2 (col_stats pass eliminated -- stats came from conv1)
  bn_finalize_k<CB><<<1, CB, 0, stream>>>(sums2, gamma2, beta2, sc2, n);
  bn_apply_k<CB, false><<<(n * CB / 4 + 255) / 256, 256, 0, stream>>>(out1, sc2, hb2, nullptr, n * CB);

  // conv2 + fused NiN shortcut
  conv_k<CB, true, false><<<(n + 127) / 128, 512, 0, stream>>>(hb2, w2t, nbr, mbits, fb, wnt, zpage, out, nullptr, n);
}